// Round 16
// baseline (495.194 us; speedup 1.0000x reference)
//
#include <hip/hip_runtime.h>
#include <hip/hip_bf16.h>
#include <math.h>

constexpr int BATCH = 1024;
typedef unsigned short u16;
typedef unsigned long long u64;
typedef __attribute__((ext_vector_type(8))) short bf16x8;
typedef __attribute__((ext_vector_type(4))) float f32x4;
typedef __attribute__((ext_vector_type(16))) float f32x16;

__device__ __forceinline__ u16 f2bf(float f) {
    union { __hip_bfloat16 b; u16 s; } u; u.b = __float2bfloat16(f); return u.s;
}
__device__ __forceinline__ f32x4 mfma16(bf16x8 a, bf16x8 b, f32x4 c) {
    return __builtin_amdgcn_mfma_f32_16x16x32_bf16(a, b, c, 0, 0, 0);
}
__device__ __forceinline__ f32x16 mfma32(bf16x8 a, bf16x8 b, f32x16 c) {
    return __builtin_amdgcn_mfma_f32_32x32x16_bf16(a, b, c, 0, 0, 0);
}

// ---------------------------------------------------------------------------
// One-time prep — weights only. K-major tables: wave B-loads are coalesced
// reads served from L2.
// ---------------------------------------------------------------------------
__global__ __launch_bounds__(256)
void prep_all(const float* __restrict__ c1w, const float* __restrict__ c2w,
              const float* __restrict__ c3w, const float* __restrict__ c4w,
              const float* __restrict__ f1w, const float* __restrict__ f2w,
              u16* __restrict__ W1t, u16* __restrict__ W2g,
              u16* __restrict__ W3g, u16* __restrict__ W4g,
              u16* __restrict__ W1b, u16* __restrict__ W2b)
{
    int id = blockIdx.x * 256 + threadIdx.x;
    constexpr int NW1B = 819200;        // float4 items
    constexpr int NW2B = 131072;        // float4 items
    if (id < NW1B) {
        float4 v = ((const float4*)f1w)[id];
        u16 p[4] = { f2bf(v.x), f2bf(v.y), f2bf(v.z), f2bf(v.w) };
        *(u64*)(W1b + (size_t)id * 4) = *(u64*)p;
        return;
    }
    id -= NW1B;
    if (id < NW2B) {
        float4 v = ((const float4*)f2w)[id];
        u16 p[4] = { f2bf(v.x), f2bf(v.y), f2bf(v.z), f2bf(v.w) };
        *(u64*)(W2b + (size_t)id * 4) = *(u64*)p;
        return;
    }
    id -= NW2B;
    if (id < 2048) {                    // W1t [16][128]
        int oc = id >> 7, k = id & 127, tap = k >> 2, ic = k & 3;
        W1t[id] = (ic < 3 && tap < 25) ? f2bf(c1w[oc * 75 + ic * 25 + tap]) : (u16)0;
        return;
    }
    id -= 2048;
    if (id < 12800) {                   // W2g: ks*512 + o32*16 + hi*8 + j
        int ks = id / 512, r = id & 511;
        int o32 = r >> 4, hi = (r >> 3) & 1, j = r & 7;
        int k = ks * 16 + hi * 8 + j;
        W2g[id] = f2bf(c2w[o32 * 400 + (k & 15) * 25 + (k >> 4)]);
        return;
    }
    id -= 12800;
    if (id < 18432) {                   // W3g: ocg*9216 + s*512 + o32*16 + hi*8 + j
        int ocg = id / 9216, r = id % 9216;
        int s = r / 512, r2 = r & 511;
        int o32 = r2 >> 4, hi = (r2 >> 3) & 1, j = r2 & 7;
        int k = s * 16 + hi * 8 + j;
        W3g[id] = f2bf(c3w[(ocg * 32 + o32) * 288 + (k & 31) * 9 + (k >> 5)]);
        return;
    }
    id -= 18432;
    if (id < 73728) {                   // W4g: ((ocg*18+ks)*2+half)*512 + (lr*4+lg)*8 + j
        int ocg = id / 18432, r = id % 18432;
        int ks = r / 1024, r2 = r & 1023;
        int half = r2 >> 9, r3 = r2 & 511;
        int lr = r3 >> 5, r4 = r3 & 31;
        int lg = r4 >> 3, j = r4 & 7;
        int k = ks * 32 + lg * 8 + j;
        int oc = ocg * 32 + half * 16 + lr;
        W4g[id] = f2bf(c4w[oc * 576 + (k & 63) * 9 + (k >> 6)]);
    }
}

// ---------------------------------------------------------------------------
// Fused conv1 + bn1 + conv2 + bn2 + pool (R15 form, unchanged).
// ---------------------------------------------------------------------------
__global__ __launch_bounds__(512, 6)
void conv12_fused(const float* __restrict__ x,
                  const u16* __restrict__ W1t, const u16* __restrict__ W2g,
                  const float* __restrict__ c1b,
                  const float* __restrict__ b1s, const float* __restrict__ b1b,
                  const float* __restrict__ b1m, const float* __restrict__ b1v,
                  const float* __restrict__ c2b,
                  const float* __restrict__ b2s, const float* __restrict__ b2b,
                  const float* __restrict__ b2m, const float* __restrict__ b2v,
                  u16* __restrict__ out)
{
    __shared__ __align__(16) unsigned char S[38624];
    float* s_bn1 = (float*)(S + 38048);
    float* s_bn2 = (float*)(S + 38240);

    const int tid = threadIdx.x;
    int bid = blockIdx.x;
    const int qx = bid & 1, qy = (bid >> 1) & 1, img = bid >> 2;

    const float* xI = x + (size_t)img * 10800 + (qy * 26) * 60 + qx * 26;
    for (int i = tid; i < 34 * 34; i += 512) {
        int yy = i / 34, xx = i - yy * 34;
        const float* p = xI + yy * 60 + xx;
        u16 pk[4];
        pk[0] = f2bf(p[0]); pk[1] = f2bf(p[3600]); pk[2] = f2bf(p[7200]); pk[3] = 0;
        *(u64*)(S + 28800 + i * 8) = *(u64*)pk;
    }
    if (tid < 16) {
        float sc = b1s[tid] * rsqrtf(b1v[tid] + 1e-5f);
        s_bn1[tid] = c1b[tid]; s_bn1[16 + tid] = sc; s_bn1[32 + tid] = b1b[tid] - b1m[tid] * sc;
    } else if (tid >= 32 && tid < 64) {
        int t = tid - 32;
        float sc = b2s[t] * rsqrtf(b2v[t] + 1e-5f);
        s_bn2[t] = c2b[t]; s_bn2[32 + t] = sc; s_bn2[64 + t] = b2b[t] - b2m[t] * sc;
    }
    __syncthreads();

    const int wv = tid >> 6, lr = tid & 15, lg = (tid >> 4) & 3;
    const int o32 = tid & 31, hi = (tid >> 5) & 1;

    {
        int toff[4][2];
        #pragma unroll
        for (int ks = 0; ks < 4; ++ks)
            #pragma unroll
            for (int h = 0; h < 2; ++h) {
                int t = ks * 8 + lg * 2 + h; if (t > 24) t = 24;
                int ky = t / 5;
                toff[ks][h] = (ky * 34 + (t - ky * 5)) * 8;
            }
        bf16x8 wb[4];
        #pragma unroll
        for (int ks = 0; ks < 4; ++ks)
            wb[ks] = *(const bf16x8*)(W1t + lr * 128 + ks * 32 + lg * 8);
        float4 bnB = *(const float4*)(s_bn1 + lg * 4);
        float4 bnS = *(const float4*)(s_bn1 + 16 + lg * 4);
        float4 bnH = *(const float4*)(s_bn1 + 32 + lg * 4);
        #pragma unroll
        for (int mi = 0; mi < 8; ++mi) {
            int t = wv + mi * 8;
            if (t < 57) {
                int pos = t * 16 + lr;
                int pc = pos > 899 ? 899 : pos;
                int py = pc / 30;
                int pb = (py * 34 + (pc - py * 30)) * 8;
                f32x4 a = {0.f, 0.f, 0.f, 0.f};
                #pragma unroll
                for (int ks = 0; ks < 4; ++ks) {
                    union { u64 v[2]; bf16x8 f; } xf;
                    xf.v[0] = *(const u64*)(S + 28800 + pb + toff[ks][0]);
                    xf.v[1] = *(const u64*)(S + 28800 + pb + toff[ks][1]);
                    a = mfma16(wb[ks], xf.f, a);
                }
                if (pos < 900) {
                    u16 q[4];
                    q[0] = f2bf(fmaxf(a[0] + bnB.x, 0.f) * bnS.x + bnH.x);
                    q[1] = f2bf(fmaxf(a[1] + bnB.y, 0.f) * bnS.y + bnH.y);
                    q[2] = f2bf(fmaxf(a[2] + bnB.z, 0.f) * bnS.z + bnH.z);
                    q[3] = f2bf(fmaxf(a[3] + bnB.w, 0.f) * bnS.w + bnH.w);
                    *(u64*)(S + pos * 32 + lg * 8) = *(u64*)q;
                }
            }
        }
    }
    __syncthreads();

    f32x16 acc[3];
    #pragma unroll
    for (int mi = 0; mi < 3; ++mi)
        #pragma unroll
        for (int j = 0; j < 16; ++j) acc[mi][j] = 0.f;
    int pbase[3];
    #pragma unroll
    for (int mi = 0; mi < 3; ++mi) {
        int tt = wv + mi * 8; if (tt > 21) tt = 21;
        int row = tt * 32 + o32;
        int q = row >> 2; if (q > 168) q = 168;
        int Q = row & 3;
        int y2 = 2 * (q / 13) + (Q >> 1);
        int x2 = 2 * (q - (q / 13) * 13) + (Q & 1);
        pbase[mi] = (y2 * 30 + x2) * 32 + hi * 16;
    }
    const bf16x8* W2v = (const bf16x8*)W2g;
    const int bidx = o32 * 2 + hi;
    #pragma unroll
    for (int ks = 0; ks < 25; ++ks) {
        bf16x8 b = W2v[ks * 64 + bidx];
        const int dp = ((ks / 5) * 30 + (ks % 5)) * 32;
        #pragma unroll
        for (int mi = 0; mi < 3; ++mi) {
            bf16x8 a = *(const bf16x8*)(S + pbase[mi] + dp);
            acc[mi] = mfma32(a, b, acc[mi]);
        }
    }
    u16* outI = out + (size_t)img * 676 * 32;
    float bnb = s_bn2[o32], bns = s_bn2[32 + o32], bnh = s_bn2[64 + o32];
    #pragma unroll
    for (int mi = 0; mi < 3; ++mi) {
        int tt = wv + mi * 8;
        if (tt < 22) {
            #pragma unroll
            for (int rg = 0; rg < 4; ++rg) {
                int quad = tt * 8 + 2 * rg + hi;
                if (quad < 169) {
                    float m = -3.4e38f;
                    #pragma unroll
                    for (int r = 0; r < 4; ++r)
                        m = fmaxf(m, fmaxf(acc[mi][rg * 4 + r] + bnb, 0.f) * bns + bnh);
                    int py = quad / 13, px = quad - (quad / 13) * 13;
                    int gpos = (qy * 13 + py) * 26 + qx * 13 + px;
                    outI[gpos * 32 + o32] = f2bf(m);
                }
            }
        }
    }
}

// ---------------------------------------------------------------------------
// conv3 via 32x32x16: block = IMG (both oc-halves, input staged ONCE, two
// compute passes). 576 threads = 9 waves.
// LDS: s_in 43264 + s_bn 768 = 44,032 B.
// ---------------------------------------------------------------------------
__global__ __launch_bounds__(576, 6)
void conv3_mfma(const u16* __restrict__ in, const u16* __restrict__ W3g,
                const float* __restrict__ cbias,
                const float* __restrict__ bns, const float* __restrict__ bnb,
                const float* __restrict__ bnm, const float* __restrict__ bnv,
                u16* __restrict__ out)
{
    __shared__ __align__(16) unsigned char S[44032];
    float* s_bn = (float*)(S + 43264);   // [3][64]

    const int tid = threadIdx.x;
    const int img = blockIdx.x;

    const u16* inI = in + (size_t)img * 676 * 32;
    for (int g = tid; g < 2704; g += 576) {
        int pa = g * 16;
        int off = pa ^ ((pa >> 2) & 0x20);
        *(bf16x8*)(S + off) = *(const bf16x8*)(inI + g * 8);
    }
    if (tid < 64) {
        float sc = bns[tid] * rsqrtf(bnv[tid] + 1e-5f);
        s_bn[tid] = cbias[tid]; s_bn[64 + tid] = sc; s_bn[128 + tid] = bnb[tid] - bnm[tid] * sc;
    }
    __syncthreads();

    const int wv = tid >> 6;
    const int o32 = tid & 31, hi = (tid >> 5) & 1;
    int pbase[2];
    #pragma unroll
    for (int mi = 0; mi < 2; ++mi) {
        int tt = wv * 2 + mi;
        int row = tt * 32 + o32;
        int q = row >> 2, Q = row & 3;
        int y2 = 2 * (q / 12) + (Q >> 1);
        int x2 = 2 * (q - (q / 12) * 12) + (Q & 1);
        pbase[mi] = (y2 * 26 + x2) * 64 + hi * 16;
    }
    const bf16x8* W3v = (const bf16x8*)W3g;

    #pragma unroll 1
    for (int ocg = 0; ocg < 2; ++ocg) {
        f32x16 acc[2];
        #pragma unroll
        for (int mi = 0; mi < 2; ++mi)
            #pragma unroll
            for (int j = 0; j < 16; ++j) acc[mi][j] = 0.f;
        const int bidx = ocg * 1152 + o32 * 2 + hi;
        bf16x8 b0 = W3v[bidx], b1 = W3v[bidx + 64], b2 = W3v[bidx + 128];
        #define C3_STEP(KS, BREG)                                               \
            {                                                                   \
                const int cell = (KS) >> 1;                                     \
                const int dp = ((cell / 3) * 26 + (cell % 3)) * 64 + ((KS) & 1) * 32; \
                _Pragma("unroll")                                               \
                for (int mi = 0; mi < 2; ++mi) {                                \
                    int pa = pbase[mi] + dp;                                    \
                    bf16x8 a = *(const bf16x8*)(S + (pa ^ ((pa >> 2) & 0x20))); \
                    acc[mi] = mfma32(a, BREG, acc[mi]);                         \
                }                                                               \
                if ((KS) + 3 < 18) BREG = W3v[bidx + ((KS) + 3) * 64];          \
            }
        #pragma unroll
        for (int g = 0; g < 6; ++g) {
            C3_STEP(g * 3 + 0, b0)
            C3_STEP(g * 3 + 1, b1)
            C3_STEP(g * 3 + 2, b2)
        }
        #undef C3_STEP
        u16* outI = out + (size_t)img * 144 * 64 + ocg * 32;
        const int loc = ocg * 32 + o32;
        float bnbv = s_bn[loc], bnsv = s_bn[64 + loc], bnhv = s_bn[128 + loc];
        #pragma unroll
        for (int mi = 0; mi < 2; ++mi) {
            int tt = wv * 2 + mi;
            #pragma unroll
            for (int rg = 0; rg < 4; ++rg) {
                int quad = tt * 8 + 2 * rg + hi;
                float m = -3.4e38f;
                #pragma unroll
                for (int r = 0; r < 4; ++r)
                    m = fmaxf(m, fmaxf(acc[mi][rg * 4 + r] + bnbv, 0.f) * bnsv + bnhv);
                outI[quad * 64 + o32] = f2bf(m);
            }
        }
    }
}

// ---------------------------------------------------------------------------
// conv4 MFMA16: block = (img, oc-PAIR); input staged once, two compute
// passes over the pair's two oc-groups. 256 threads.
// LDS: s_in 18432 + s_bn 768 = 19,200 B -> 8 blocks/CU.
// ---------------------------------------------------------------------------
__global__ __launch_bounds__(256, 8)
void conv4_mfma(const u16* __restrict__ in, const u16* __restrict__ W4g,
                const float* __restrict__ cbias,
                const float* __restrict__ bns, const float* __restrict__ bnb,
                const float* __restrict__ bnm, const float* __restrict__ bnv,
                u16* __restrict__ out)
{
    __shared__ __align__(16) unsigned char S[19200];
    float* s_bn = (float*)(S + 18432);   // [3][64]

    const int tid = threadIdx.x;
    const int ocp = blockIdx.x & 1;      // oc-pair: groups {2*ocp, 2*ocp+1}
    const int img = blockIdx.x >> 1;

    const u16* inI = in + (size_t)img * 144 * 64;
    for (int g = tid; g < 144 * 8; g += 256) {
        int pos = g >> 3, part = g & 7;
        int off = (pos * 128 + part * 16) ^ ((pos & 7) << 4);
        *(bf16x8*)(S + off) = *(const bf16x8*)(inI + g * 8);
    }
    if (tid < 64) {
        int oc = ocp * 64 + tid;
        float sc = bns[oc] * rsqrtf(bnv[oc] + 1e-5f);
        s_bn[tid] = cbias[oc]; s_bn[64 + tid] = sc; s_bn[128 + tid] = bnb[oc] - bnm[oc] * sc;
    }
    __syncthreads();

    const int w = tid >> 6, lr = tid & 15, lg = (tid >> 4) & 3;
    int pb7[2];
    #pragma unroll
    for (int mi = 0; mi < 2; ++mi) {
        int aq = (w + mi * 4) * 4 + (lr >> 2);
        if (aq > 24) aq = 24;
        int y2 = 2 * (aq / 5) + ((lr >> 1) & 1);
        int x2 = 2 * (aq % 5) + (lr & 1);
        pb7[mi] = ((y2 * 12 + x2) << 7) + lg * 16;
    }
    const bf16x8* W4v = (const bf16x8*)W4g;
    u16* outI = out + (size_t)img * 3200;

    #pragma unroll 1
    for (int pass = 0; pass < 2; ++pass) {
        const int ocg = ocp * 2 + pass;
        f32x4 acc[2][2];
        {
            f32x4 z = {0.f, 0.f, 0.f, 0.f};
            acc[0][0] = z; acc[0][1] = z; acc[1][0] = z; acc[1][1] = z;
        }
        const int base = ocg * 2304 + lr * 4 + lg;
        bf16x8 s0a = W4v[base],       s0b = W4v[base + 64];
        bf16x8 s1a = W4v[base + 128], s1b = W4v[base + 192];
        #define C4_STEP(KS, BA, BB)                                             \
            {                                                                   \
                const int cell = (KS) >> 1;                                     \
                const int dp7 = (((cell / 3) * 12 + (cell % 3)) << 7) + ((KS) & 1) * 64; \
                _Pragma("unroll")                                               \
                for (int mi = 0; mi < 2; ++mi) {                                \
                    int pa = pb7[mi] + dp7;                                     \
                    int off = pa ^ ((pa >> 3) & 0x70);                          \
                    bf16x8 a = *(const bf16x8*)(S + off);                       \
                    acc[mi][0] = mfma16(a, BA, acc[mi][0]);                     \
                    acc[mi][1] = mfma16(a, BB, acc[mi][1]);                     \
                }                                                               \
                if ((KS) + 2 < 18) {                                            \
                    BA = W4v[base + ((KS) + 2) * 128];                          \
                    BB = W4v[base + ((KS) + 2) * 128 + 64];                     \
                }                                                               \
            }
        #pragma unroll
        for (int g = 0; g < 9; ++g) {
            C4_STEP(2 * g,     s0a, s0b)
            C4_STEP(2 * g + 1, s1a, s1b)
        }
        #undef C4_STEP
        const int loc = pass * 32 + lr;
        float bc0 = s_bn[loc],      sc0 = s_bn[64 + loc],  sh0 = s_bn[128 + loc];
        float bc1 = s_bn[loc + 16], sc1 = s_bn[80 + loc],  sh1 = s_bn[144 + loc];
        #pragma unroll
        for (int mi = 0; mi < 2; ++mi) {
            int quad = (w + mi * 4) * 4 + lg;
            if (quad < 25) {
                float m0 = -3.4e38f, m1 = -3.4e38f;
                #pragma unroll
                for (int r2 = 0; r2 < 4; ++r2) {
                    m0 = fmaxf(m0, fmaxf(acc[mi][0][r2] + bc0, 0.f) * sc0 + sh0);
                    m1 = fmaxf(m1, fmaxf(acc[mi][1][r2] + bc1, 0.f) * sc1 + sh1);
                }
                outI[(ocg * 32 + lr) * 25 + quad]      = f2bf(m0);
                outI[(ocg * 32 + 16 + lr) * 25 + quad] = f2bf(m1);
            }
        }
    }
}

// ---------------------------------------------------------------------------
// fc GEMM with global->reg double-buffered staging (kept).
// ---------------------------------------------------------------------------
template<bool OUTF32>
__global__ __launch_bounds__(256)
void fc_gemm_bf(const u16* __restrict__ A, const u16* __restrict__ Wb,
                const float* __restrict__ bias, void* __restrict__ outv,
                int M, int N, int K)
{
    __shared__ __align__(16) unsigned char S[34816];   // sA 64x272 | sB 64x272
    const int tid = threadIdx.x;
    const int n0 = blockIdx.x * 64, m0 = blockIdx.y * 64;
    const int w = tid >> 6, lr = tid & 15, lg = (tid >> 4) & 3;
    const int r = tid >> 2, c = tid & 3;

    f32x4 acc[4];
    { f32x4 z = {0.f,0.f,0.f,0.f}; acc[0]=z; acc[1]=z; acc[2]=z; acc[3]=z; }

    const u16* Ab = A  + (size_t)(m0 + r) * K + c * 8;
    const u16* Bb = Wb + (size_t)(n0 + r) * K + c * 8;
    unsigned char* sAw = S + r * 272 + c * 16;
    unsigned char* sBw = S + 17408 + r * 272 + c * 16;

    bf16x8 ra[4], rb[4];
    #pragma unroll
    for (int q = 0; q < 4; ++q) {
        ra[q] = *(const bf16x8*)(Ab + q * 32);
        rb[q] = *(const bf16x8*)(Bb + q * 32);
    }
    for (int k0 = 0; k0 < K; k0 += 128) {
        #pragma unroll
        for (int q = 0; q < 4; ++q) {
            *(bf16x8*)(sAw + q * 64) = ra[q];
            *(bf16x8*)(sBw + q * 64) = rb[q];
        }
        __syncthreads();
        if (k0 + 128 < K) {
            #pragma unroll
            for (int q = 0; q < 4; ++q) {
                ra[q] = *(const bf16x8*)(Ab + k0 + 128 + q * 32);
                rb[q] = *(const bf16x8*)(Bb + k0 + 128 + q * 32);
            }
        }
        #pragma unroll
        for (int k32 = 0; k32 < 4; ++k32) {
            bf16x8 a = *(const bf16x8*)(S + (w * 16 + lr) * 272 + k32 * 64 + lg * 16);
            #pragma unroll
            for (int nt = 0; nt < 4; ++nt) {
                bf16x8 b = *(const bf16x8*)(S + 17408 + (nt * 16 + lr) * 272 + k32 * 64 + lg * 16);
                acc[nt] = mfma16(a, b, acc[nt]);
            }
        }
        __syncthreads();
    }
    #pragma unroll
    for (int nt = 0; nt < 4; ++nt) {
        int col = n0 + nt * 16 + lr;
        float bv = bias[col];
        #pragma unroll
        for (int r2 = 0; r2 < 4; ++r2) {
            int row = m0 + w * 16 + lg * 4 + r2;
            float v = fmaxf(acc[nt][r2] + bv, 0.f);
            if (OUTF32) ((float*)outv)[(size_t)row * N + col] = v;
            else        ((u16*)outv)[(size_t)row * N + col] = f2bf(v);
        }
    }
}

// ---------------------------------------------------------------------------
// Fused fc3 (512->37) + sigmoid + sequential normalize + dep-multiply.
// ---------------------------------------------------------------------------
__global__ __launch_bounds__(256)
void fc3_norm(const float* __restrict__ A, const float* __restrict__ W,
              const float* __restrict__ bias, float* __restrict__ out)
{
    __shared__ float sp[4][40];
    const int v = threadIdx.x >> 6, lane = threadIdx.x & 63;
    const int img = blockIdx.x * 4 + v;

    if (lane < 37) {
        const float4* a4 = (const float4*)(A + (size_t)img * 512);
        const float4* w4 = (const float4*)(W + (size_t)lane * 512);
        float s = bias[lane];
        #pragma unroll 4
        for (int k = 0; k < 128; ++k) {
            float4 a = a4[k], ww = w4[k];
            s = fmaf(a.x, ww.x, s); s = fmaf(a.y, ww.y, s);
            s = fmaf(a.z, ww.z, s); s = fmaf(a.w, ww.w, s);
        }
        sp[v][lane] = 1.f / (1.f + expf(-s));
    }
    __syncthreads();
    if (lane == 0) {
        float xv[37];
        #pragma unroll
        for (int i = 0; i < 37; ++i) xv[i] = sp[v][i];
        const int ss[11]  = {0, 3, 5, 7, 9, 13, 15, 18, 25, 28, 31};
        const int ee[11]  = {3, 5, 7, 9, 13, 15, 18, 25, 28, 31, 37};
        const int dep[11] = {-1, 1, 4, 4, 4, -1, 0, 13, 3, 7, 7};
        #pragma unroll
        for (int i = 0; i < 11; ++i) {
            for (int j = ss[i]; j < ee[i]; ++j) {
                float ssum = 0.f;
                for (int cix = ss[i]; cix < ee[i]; ++cix) ssum += xv[cix];
                xv[j] = xv[j] / (ssum + 1e-12f);
            }
        }
        #pragma unroll
        for (int i = 0; i < 11; ++i) {
            if (dep[i] >= 0) {
                const float m = xv[dep[i]];
                for (int cix = ss[i]; cix < ee[i]; ++cix) xv[cix] *= m;
            }
        }
        #pragma unroll
        for (int i = 0; i < 37; ++i) sp[v][i] = xv[i];
    }
    __syncthreads();
    if (lane < 37) out[(size_t)img * 37 + lane] = sp[v][lane];
}

// ---------------------------------------------------------------------------
extern "C" void kernel_launch(void* const* d_in, const int* in_sizes, int n_in,
                              void* d_out, int out_size, void* d_ws, size_t ws_size,
                              hipStream_t stream)
{
    const float* x   = (const float*)d_in[0];
    const float* c1w = (const float*)d_in[1];  const float* c1b = (const float*)d_in[2];
    const float* b1s = (const float*)d_in[3];  const float* b1b = (const float*)d_in[4];
    const float* b1m = (const float*)d_in[5];  const float* b1v = (const float*)d_in[6];
    const float* c2w = (const float*)d_in[7];  const float* c2b = (const float*)d_in[8];
    const float* b2s = (const float*)d_in[9];  const float* b2b = (const float*)d_in[10];
    const float* b2m = (const float*)d_in[11]; const float* b2v = (const float*)d_in[12];
    const float* c3w = (const float*)d_in[13]; const float* c3b = (const float*)d_in[14];
    const float* b3s = (const float*)d_in[15]; const float* b3b = (const float*)d_in[16];
    const float* b3m = (const float*)d_in[17]; const float* b3v = (const float*)d_in[18];
    const float* c4w = (const float*)d_in[19]; const float* c4b = (const float*)d_in[20];
    const float* b4s = (const float*)d_in[21]; const float* b4b = (const float*)d_in[22];
    const float* b4m = (const float*)d_in[23]; const float* b4v = (const float*)d_in[24];
    const float* f1w = (const float*)d_in[25]; const float* f1b = (const float*)d_in[26];
    const float* f2w = (const float*)d_in[27]; const float* f2b = (const float*)d_in[28];
    const float* f3w = (const float*)d_in[29]; const float* f3b = (const float*)d_in[30];

    // Workspace (bytes), peak ~81.7 MB (unchanged layout):
    u16*   P2  = (u16*)d_ws;
    u16*   P3  = (u16*)((char*)d_ws + 44302336);
    u16*   P4  = (u16*)((char*)d_ws + 63176704);
    u16*   F1  = (u16*)((char*)d_ws + 69730304);
    float* F2  = (float*)((char*)d_ws + 71827456);
    u16*   W1b = (u16*)((char*)d_ws + 73924608);
    u16*   W2b = (u16*)((char*)d_ws + 80478208);
    u16*   W1t = (u16*)((char*)d_ws + 81526784);
    u16*   W2g = (u16*)((char*)d_ws + 81530880);
    u16*   W3g = (u16*)((char*)d_ws + 81556480);
    u16*   W4g = (u16*)((char*)d_ws + 81593344);

    prep_all<<<4130, 256, 0, stream>>>(c1w, c2w, c3w, c4w, f1w, f2w,
                                       W1t, W2g, W3g, W4g, W1b, W2b);

    conv12_fused<<<BATCH * 4, 512, 0, stream>>>(x, W1t, W2g, c1b, b1s, b1b, b1m, b1v,
                                                c2b, b2s, b2b, b2m, b2v, P2);
    conv3_mfma<<<BATCH, 576, 0, stream>>>(P2, W3g, c3b, b3s, b3b, b3m, b3v, P3);
    conv4_mfma<<<BATCH * 2, 256, 0, stream>>>(P3, W4g, c4b, b4s, b4b, b4m, b4v, P4);

    fc_gemm_bf<false><<<dim3(16, 16), 256, 0, stream>>>(P4, W1b, f1b, F1, 1024, 1024, 3200);
    fc_gemm_bf<true ><<<dim3(8, 16),  256, 0, stream>>>(F1, W2b, f2b, F2, 1024, 512, 1024);
    fc3_norm<<<BATCH / 4, 256, 0, stream>>>(F2, f3w, f3b, (float*)d_out);
}

// Round 17
// 231.570 us; speedup vs baseline: 2.1384x; 2.1384x over previous
//
#include <hip/hip_runtime.h>
#include <hip/hip_bf16.h>
#include <math.h>

constexpr int BATCH = 1024;
typedef unsigned short u16;
typedef unsigned long long u64;
typedef __attribute__((ext_vector_type(8))) short bf16x8;
typedef __attribute__((ext_vector_type(4))) float f32x4;
typedef __attribute__((ext_vector_type(16))) float f32x16;

__device__ __forceinline__ u16 f2bf(float f) {
    union { __hip_bfloat16 b; u16 s; } u; u.b = __float2bfloat16(f); return u.s;
}
__device__ __forceinline__ f32x4 mfma16(bf16x8 a, bf16x8 b, f32x4 c) {
    return __builtin_amdgcn_mfma_f32_16x16x32_bf16(a, b, c, 0, 0, 0);
}
__device__ __forceinline__ f32x16 mfma32(bf16x8 a, bf16x8 b, f32x16 c) {
    return __builtin_amdgcn_mfma_f32_32x32x16_bf16(a, b, c, 0, 0, 0);
}

// ---------------------------------------------------------------------------
// One-time prep — weights only. K-major tables: wave B-loads are coalesced
// reads served from L2.
// ---------------------------------------------------------------------------
__global__ __launch_bounds__(256)
void prep_all(const float* __restrict__ c1w, const float* __restrict__ c2w,
              const float* __restrict__ c3w, const float* __restrict__ c4w,
              const float* __restrict__ f1w, const float* __restrict__ f2w,
              u16* __restrict__ W1t, u16* __restrict__ W2g,
              u16* __restrict__ W3g, u16* __restrict__ W4g,
              u16* __restrict__ W1b, u16* __restrict__ W2b)
{
    int id = blockIdx.x * 256 + threadIdx.x;
    constexpr int NW1B = 819200;        // float4 items
    constexpr int NW2B = 131072;        // float4 items
    if (id < NW1B) {
        float4 v = ((const float4*)f1w)[id];
        u16 p[4] = { f2bf(v.x), f2bf(v.y), f2bf(v.z), f2bf(v.w) };
        *(u64*)(W1b + (size_t)id * 4) = *(u64*)p;
        return;
    }
    id -= NW1B;
    if (id < NW2B) {
        float4 v = ((const float4*)f2w)[id];
        u16 p[4] = { f2bf(v.x), f2bf(v.y), f2bf(v.z), f2bf(v.w) };
        *(u64*)(W2b + (size_t)id * 4) = *(u64*)p;
        return;
    }
    id -= NW2B;
    if (id < 2048) {                    // W1t [16][128]
        int oc = id >> 7, k = id & 127, tap = k >> 2, ic = k & 3;
        W1t[id] = (ic < 3 && tap < 25) ? f2bf(c1w[oc * 75 + ic * 25 + tap]) : (u16)0;
        return;
    }
    id -= 2048;
    if (id < 12800) {                   // W2g: ks*512 + o32*16 + hi*8 + j
        int ks = id / 512, r = id & 511;
        int o32 = r >> 4, hi = (r >> 3) & 1, j = r & 7;
        int k = ks * 16 + hi * 8 + j;
        W2g[id] = f2bf(c2w[o32 * 400 + (k & 15) * 25 + (k >> 4)]);
        return;
    }
    id -= 12800;
    if (id < 18432) {                   // W3g: ocg*9216 + s*512 + o32*16 + hi*8 + j
        int ocg = id / 9216, r = id % 9216;
        int s = r / 512, r2 = r & 511;
        int o32 = r2 >> 4, hi = (r2 >> 3) & 1, j = r2 & 7;
        int k = s * 16 + hi * 8 + j;
        W3g[id] = f2bf(c3w[(ocg * 32 + o32) * 288 + (k & 31) * 9 + (k >> 5)]);
        return;
    }
    id -= 18432;
    if (id < 73728) {                   // W4g: ((ocg*18+ks)*2+half)*512 + (lr*4+lg)*8 + j
        int ocg = id / 18432, r = id % 18432;
        int ks = r / 1024, r2 = r & 1023;
        int half = r2 >> 9, r3 = r2 & 511;
        int lr = r3 >> 5, r4 = r3 & 31;
        int lg = r4 >> 3, j = r4 & 7;
        int k = ks * 32 + lg * 8 + j;
        int oc = ocg * 32 + half * 16 + lr;
        W4g[id] = f2bf(c4w[oc * 576 + (k & 63) * 9 + (k >> 6)]);
    }
}

// ---------------------------------------------------------------------------
// Fused conv1 + bn1 + conv2 + bn2 + pool. Block = (img, quadrant), 512 thr.
// x staged inline from f32; conv1/conv2 weights from L2 (plain loads —
// every explicit prefetch variant regressed in R12/R13/R16 A/B).
// LDS: s_c1 28800 + s_x 9248 + bn 576 = 38,624 B.
// ---------------------------------------------------------------------------
__global__ __launch_bounds__(512, 6)
void conv12_fused(const float* __restrict__ x,
                  const u16* __restrict__ W1t, const u16* __restrict__ W2g,
                  const float* __restrict__ c1b,
                  const float* __restrict__ b1s, const float* __restrict__ b1b,
                  const float* __restrict__ b1m, const float* __restrict__ b1v,
                  const float* __restrict__ c2b,
                  const float* __restrict__ b2s, const float* __restrict__ b2b,
                  const float* __restrict__ b2m, const float* __restrict__ b2v,
                  u16* __restrict__ out)
{
    __shared__ __align__(16) unsigned char S[38624];
    float* s_bn1 = (float*)(S + 38048);
    float* s_bn2 = (float*)(S + 38240);

    const int tid = threadIdx.x;
    int bid = blockIdx.x;
    const int qx = bid & 1, qy = (bid >> 1) & 1, img = bid >> 2;

    const float* xI = x + (size_t)img * 10800 + (qy * 26) * 60 + qx * 26;
    for (int i = tid; i < 34 * 34; i += 512) {
        int yy = i / 34, xx = i - yy * 34;
        const float* p = xI + yy * 60 + xx;
        u16 pk[4];
        pk[0] = f2bf(p[0]); pk[1] = f2bf(p[3600]); pk[2] = f2bf(p[7200]); pk[3] = 0;
        *(u64*)(S + 28800 + i * 8) = *(u64*)pk;
    }
    if (tid < 16) {
        float sc = b1s[tid] * rsqrtf(b1v[tid] + 1e-5f);
        s_bn1[tid] = c1b[tid]; s_bn1[16 + tid] = sc; s_bn1[32 + tid] = b1b[tid] - b1m[tid] * sc;
    } else if (tid >= 32 && tid < 64) {
        int t = tid - 32;
        float sc = b2s[t] * rsqrtf(b2v[t] + 1e-5f);
        s_bn2[t] = c2b[t]; s_bn2[32 + t] = sc; s_bn2[64 + t] = b2b[t] - b2m[t] * sc;
    }
    __syncthreads();

    const int wv = tid >> 6, lr = tid & 15, lg = (tid >> 4) & 3;
    const int o32 = tid & 31, hi = (tid >> 5) & 1;

    {
        int toff[4][2];
        #pragma unroll
        for (int ks = 0; ks < 4; ++ks)
            #pragma unroll
            for (int h = 0; h < 2; ++h) {
                int t = ks * 8 + lg * 2 + h; if (t > 24) t = 24;
                int ky = t / 5;
                toff[ks][h] = (ky * 34 + (t - ky * 5)) * 8;
            }
        bf16x8 wb[4];
        #pragma unroll
        for (int ks = 0; ks < 4; ++ks)
            wb[ks] = *(const bf16x8*)(W1t + lr * 128 + ks * 32 + lg * 8);
        float4 bnB = *(const float4*)(s_bn1 + lg * 4);
        float4 bnS = *(const float4*)(s_bn1 + 16 + lg * 4);
        float4 bnH = *(const float4*)(s_bn1 + 32 + lg * 4);
        #pragma unroll
        for (int mi = 0; mi < 8; ++mi) {
            int t = wv + mi * 8;
            if (t < 57) {
                int pos = t * 16 + lr;
                int pc = pos > 899 ? 899 : pos;
                int py = pc / 30;
                int pb = (py * 34 + (pc - py * 30)) * 8;
                f32x4 a = {0.f, 0.f, 0.f, 0.f};
                #pragma unroll
                for (int ks = 0; ks < 4; ++ks) {
                    union { u64 v[2]; bf16x8 f; } xf;
                    xf.v[0] = *(const u64*)(S + 28800 + pb + toff[ks][0]);
                    xf.v[1] = *(const u64*)(S + 28800 + pb + toff[ks][1]);
                    a = mfma16(wb[ks], xf.f, a);
                }
                if (pos < 900) {
                    u16 q[4];
                    q[0] = f2bf(fmaxf(a[0] + bnB.x, 0.f) * bnS.x + bnH.x);
                    q[1] = f2bf(fmaxf(a[1] + bnB.y, 0.f) * bnS.y + bnH.y);
                    q[2] = f2bf(fmaxf(a[2] + bnB.z, 0.f) * bnS.z + bnH.z);
                    q[3] = f2bf(fmaxf(a[3] + bnB.w, 0.f) * bnS.w + bnH.w);
                    *(u64*)(S + pos * 32 + lg * 8) = *(u64*)q;
                }
            }
        }
    }
    __syncthreads();

    f32x16 acc[3];
    #pragma unroll
    for (int mi = 0; mi < 3; ++mi)
        #pragma unroll
        for (int j = 0; j < 16; ++j) acc[mi][j] = 0.f;
    int pbase[3];
    #pragma unroll
    for (int mi = 0; mi < 3; ++mi) {
        int tt = wv + mi * 8; if (tt > 21) tt = 21;
        int row = tt * 32 + o32;
        int q = row >> 2; if (q > 168) q = 168;
        int Q = row & 3;
        int y2 = 2 * (q / 13) + (Q >> 1);
        int x2 = 2 * (q - (q / 13) * 13) + (Q & 1);
        pbase[mi] = (y2 * 30 + x2) * 32 + hi * 16;
    }
    const bf16x8* W2v = (const bf16x8*)W2g;
    const int bidx = o32 * 2 + hi;
    #pragma unroll
    for (int ks = 0; ks < 25; ++ks) {
        bf16x8 b = W2v[ks * 64 + bidx];
        const int dp = ((ks / 5) * 30 + (ks % 5)) * 32;
        #pragma unroll
        for (int mi = 0; mi < 3; ++mi) {
            bf16x8 a = *(const bf16x8*)(S + pbase[mi] + dp);
            acc[mi] = mfma32(a, b, acc[mi]);
        }
    }
    u16* outI = out + (size_t)img * 676 * 32;
    float bnb = s_bn2[o32], bns = s_bn2[32 + o32], bnh = s_bn2[64 + o32];
    #pragma unroll
    for (int mi = 0; mi < 3; ++mi) {
        int tt = wv + mi * 8;
        if (tt < 22) {
            #pragma unroll
            for (int rg = 0; rg < 4; ++rg) {
                int quad = tt * 8 + 2 * rg + hi;
                if (quad < 169) {
                    float m = -3.4e38f;
                    #pragma unroll
                    for (int r = 0; r < 4; ++r)
                        m = fmaxf(m, fmaxf(acc[mi][rg * 4 + r] + bnb, 0.f) * bns + bnh);
                    int py = quad / 13, px = quad - (quad / 13) * 13;
                    int gpos = (qy * 13 + py) * 26 + qx * 13 + px;
                    outI[gpos * 32 + o32] = f2bf(m);
                }
            }
        }
    }
}

// ---------------------------------------------------------------------------
// conv3 via 32x32x16; named-register 3-deep B prefetch (R13/R15 form).
// Block = (img, oc-half), 576 threads = 9 waves, 18 M-tiles = 2/wave.
// ---------------------------------------------------------------------------
__global__ __launch_bounds__(576, 6)
void conv3_mfma(const u16* __restrict__ in, const u16* __restrict__ W3g,
                const float* __restrict__ cbias,
                const float* __restrict__ bns, const float* __restrict__ bnb,
                const float* __restrict__ bnm, const float* __restrict__ bnv,
                u16* __restrict__ out)
{
    __shared__ __align__(16) unsigned char S[43648];
    float* s_bn = (float*)(S + 43264);

    const int tid = threadIdx.x;
    const int ocg = blockIdx.x & 1;
    const int img = blockIdx.x >> 1;

    const u16* inI = in + (size_t)img * 676 * 32;
    for (int g = tid; g < 2704; g += 576) {
        int pa = g * 16;
        int off = pa ^ ((pa >> 2) & 0x20);
        *(bf16x8*)(S + off) = *(const bf16x8*)(inI + g * 8);
    }
    if (tid < 32) {
        int oc = ocg * 32 + tid;
        float sc = bns[oc] * rsqrtf(bnv[oc] + 1e-5f);
        s_bn[tid] = cbias[oc]; s_bn[32 + tid] = sc; s_bn[64 + tid] = bnb[oc] - bnm[oc] * sc;
    }
    __syncthreads();

    const int wv = tid >> 6;
    const int o32 = tid & 31, hi = (tid >> 5) & 1;
    f32x16 acc[2];
    #pragma unroll
    for (int mi = 0; mi < 2; ++mi)
        #pragma unroll
        for (int j = 0; j < 16; ++j) acc[mi][j] = 0.f;
    int pbase[2];
    #pragma unroll
    for (int mi = 0; mi < 2; ++mi) {
        int tt = wv * 2 + mi;
        int row = tt * 32 + o32;
        int q = row >> 2, Q = row & 3;
        int y2 = 2 * (q / 12) + (Q >> 1);
        int x2 = 2 * (q - (q / 12) * 12) + (Q & 1);
        pbase[mi] = (y2 * 26 + x2) * 64 + hi * 16;
    }
    const bf16x8* W3v = (const bf16x8*)W3g;
    const int bidx = ocg * 1152 + o32 * 2 + hi;
    bf16x8 b0 = W3v[bidx], b1 = W3v[bidx + 64], b2 = W3v[bidx + 128];
    #define C3_STEP(KS, BREG)                                               \
        {                                                                   \
            const int cell = (KS) >> 1;                                     \
            const int dp = ((cell / 3) * 26 + (cell % 3)) * 64 + ((KS) & 1) * 32; \
            _Pragma("unroll")                                               \
            for (int mi = 0; mi < 2; ++mi) {                                \
                int pa = pbase[mi] + dp;                                    \
                bf16x8 a = *(const bf16x8*)(S + (pa ^ ((pa >> 2) & 0x20))); \
                acc[mi] = mfma32(a, BREG, acc[mi]);                         \
            }                                                               \
            if ((KS) + 3 < 18) BREG = W3v[bidx + ((KS) + 3) * 64];          \
        }
    #pragma unroll
    for (int g = 0; g < 6; ++g) {
        C3_STEP(g * 3 + 0, b0)
        C3_STEP(g * 3 + 1, b1)
        C3_STEP(g * 3 + 2, b2)
    }
    #undef C3_STEP
    u16* outI = out + (size_t)img * 144 * 64 + ocg * 32;
    float bnbv = s_bn[o32], bnsv = s_bn[32 + o32], bnhv = s_bn[64 + o32];
    #pragma unroll
    for (int mi = 0; mi < 2; ++mi) {
        int tt = wv * 2 + mi;
        #pragma unroll
        for (int rg = 0; rg < 4; ++rg) {
            int quad = tt * 8 + 2 * rg + hi;
            float m = -3.4e38f;
            #pragma unroll
            for (int r = 0; r < 4; ++r)
                m = fmaxf(m, fmaxf(acc[mi][rg * 4 + r] + bnbv, 0.f) * bnsv + bnhv);
            outI[quad * 64 + o32] = f2bf(m);
        }
    }
}

// ---------------------------------------------------------------------------
// conv4 MFMA16; named-register 2-deep B prefetch (R13/R15 form).
// Block = (img, oc-quarter of 32), 256 threads.
// ---------------------------------------------------------------------------
__global__ __launch_bounds__(256, 8)
void conv4_mfma(const u16* __restrict__ in, const u16* __restrict__ W4g,
                const float* __restrict__ cbias,
                const float* __restrict__ bns, const float* __restrict__ bnb,
                const float* __restrict__ bnm, const float* __restrict__ bnv,
                u16* __restrict__ out)
{
    __shared__ __align__(16) unsigned char S[18816];
    float* s_bn = (float*)(S + 18432);

    const int tid = threadIdx.x;
    const int ocg = blockIdx.x & 3;
    const int img = blockIdx.x >> 2;

    const u16* inI = in + (size_t)img * 144 * 64;
    for (int g = tid; g < 144 * 8; g += 256) {
        int pos = g >> 3, part = g & 7;
        int off = (pos * 128 + part * 16) ^ ((pos & 7) << 4);
        *(bf16x8*)(S + off) = *(const bf16x8*)(inI + g * 8);
    }
    if (tid < 32) {
        int oc = ocg * 32 + tid;
        float sc = bns[oc] * rsqrtf(bnv[oc] + 1e-5f);
        s_bn[tid] = cbias[oc]; s_bn[32 + tid] = sc; s_bn[64 + tid] = bnb[oc] - bnm[oc] * sc;
    }
    __syncthreads();

    const int w = tid >> 6, lr = tid & 15, lg = (tid >> 4) & 3;
    f32x4 acc[2][2];
    {
        f32x4 z = {0.f, 0.f, 0.f, 0.f};
        acc[0][0] = z; acc[0][1] = z; acc[1][0] = z; acc[1][1] = z;
    }
    int pb7[2];
    #pragma unroll
    for (int mi = 0; mi < 2; ++mi) {
        int aq = (w + mi * 4) * 4 + (lr >> 2);
        if (aq > 24) aq = 24;
        int y2 = 2 * (aq / 5) + ((lr >> 1) & 1);
        int x2 = 2 * (aq % 5) + (lr & 1);
        pb7[mi] = ((y2 * 12 + x2) << 7) + lg * 16;
    }
    const bf16x8* W4v = (const bf16x8*)W4g;
    const int base = ocg * 2304 + lr * 4 + lg;
    bf16x8 s0a = W4v[base],       s0b = W4v[base + 64];
    bf16x8 s1a = W4v[base + 128], s1b = W4v[base + 192];
    #define C4_STEP(KS, BA, BB)                                             \
        {                                                                   \
            const int cell = (KS) >> 1;                                     \
            const int dp7 = (((cell / 3) * 12 + (cell % 3)) << 7) + ((KS) & 1) * 64; \
            _Pragma("unroll")                                               \
            for (int mi = 0; mi < 2; ++mi) {                                \
                int pa = pb7[mi] + dp7;                                     \
                int off = pa ^ ((pa >> 3) & 0x70);                          \
                bf16x8 a = *(const bf16x8*)(S + off);                       \
                acc[mi][0] = mfma16(a, BA, acc[mi][0]);                     \
                acc[mi][1] = mfma16(a, BB, acc[mi][1]);                     \
            }                                                               \
            if ((KS) + 2 < 18) {                                            \
                BA = W4v[base + ((KS) + 2) * 128];                          \
                BB = W4v[base + ((KS) + 2) * 128 + 64];                     \
            }                                                               \
        }
    #pragma unroll
    for (int g = 0; g < 9; ++g) {
        C4_STEP(2 * g,     s0a, s0b)
        C4_STEP(2 * g + 1, s1a, s1b)
    }
    #undef C4_STEP
    u16* outI = out + (size_t)img * 3200;
    float bc0 = s_bn[lr],      sc0 = s_bn[32 + lr], sh0 = s_bn[64 + lr];
    float bc1 = s_bn[16 + lr], sc1 = s_bn[48 + lr], sh1 = s_bn[80 + lr];
    #pragma unroll
    for (int mi = 0; mi < 2; ++mi) {
        int quad = (w + mi * 4) * 4 + lg;
        if (quad < 25) {
            float m0 = -3.4e38f, m1 = -3.4e38f;
            #pragma unroll
            for (int r2 = 0; r2 < 4; ++r2) {
                m0 = fmaxf(m0, fmaxf(acc[mi][0][r2] + bc0, 0.f) * sc0 + sh0);
                m1 = fmaxf(m1, fmaxf(acc[mi][1][r2] + bc1, 0.f) * sc1 + sh1);
            }
            outI[(ocg * 32 + lr) * 25 + quad]      = f2bf(m0);
            outI[(ocg * 32 + 16 + lr) * 25 + quad] = f2bf(m1);
        }
    }
}

// ---------------------------------------------------------------------------
// fc GEMM with global->reg double-buffered staging (R12/R15 form).
// ---------------------------------------------------------------------------
template<bool OUTF32>
__global__ __launch_bounds__(256)
void fc_gemm_bf(const u16* __restrict__ A, const u16* __restrict__ Wb,
                const float* __restrict__ bias, void* __restrict__ outv,
                int M, int N, int K)
{
    __shared__ __align__(16) unsigned char S[34816];   // sA 64x272 | sB 64x272
    const int tid = threadIdx.x;
    const int n0 = blockIdx.x * 64, m0 = blockIdx.y * 64;
    const int w = tid >> 6, lr = tid & 15, lg = (tid >> 4) & 3;
    const int r = tid >> 2, c = tid & 3;

    f32x4 acc[4];
    { f32x4 z = {0.f,0.f,0.f,0.f}; acc[0]=z; acc[1]=z; acc[2]=z; acc[3]=z; }

    const u16* Ab = A  + (size_t)(m0 + r) * K + c * 8;
    const u16* Bb = Wb + (size_t)(n0 + r) * K + c * 8;
    unsigned char* sAw = S + r * 272 + c * 16;
    unsigned char* sBw = S + 17408 + r * 272 + c * 16;

    bf16x8 ra[4], rb[4];
    #pragma unroll
    for (int q = 0; q < 4; ++q) {
        ra[q] = *(const bf16x8*)(Ab + q * 32);
        rb[q] = *(const bf16x8*)(Bb + q * 32);
    }
    for (int k0 = 0; k0 < K; k0 += 128) {
        #pragma unroll
        for (int q = 0; q < 4; ++q) {
            *(bf16x8*)(sAw + q * 64) = ra[q];
            *(bf16x8*)(sBw + q * 64) = rb[q];
        }
        __syncthreads();
        if (k0 + 128 < K) {
            #pragma unroll
            for (int q = 0; q < 4; ++q) {
                ra[q] = *(const bf16x8*)(Ab + k0 + 128 + q * 32);
                rb[q] = *(const bf16x8*)(Bb + k0 + 128 + q * 32);
            }
        }
        #pragma unroll
        for (int k32 = 0; k32 < 4; ++k32) {
            bf16x8 a = *(const bf16x8*)(S + (w * 16 + lr) * 272 + k32 * 64 + lg * 16);
            #pragma unroll
            for (int nt = 0; nt < 4; ++nt) {
                bf16x8 b = *(const bf16x8*)(S + 17408 + (nt * 16 + lr) * 272 + k32 * 64 + lg * 16);
                acc[nt] = mfma16(a, b, acc[nt]);
            }
        }
        __syncthreads();
    }
    #pragma unroll
    for (int nt = 0; nt < 4; ++nt) {
        int col = n0 + nt * 16 + lr;
        float bv = bias[col];
        #pragma unroll
        for (int r2 = 0; r2 < 4; ++r2) {
            int row = m0 + w * 16 + lg * 4 + r2;
            float v = fmaxf(acc[nt][r2] + bv, 0.f);
            if (OUTF32) ((float*)outv)[(size_t)row * N + col] = v;
            else        ((u16*)outv)[(size_t)row * N + col] = f2bf(v);
        }
    }
}

// ---------------------------------------------------------------------------
// Fused fc3 (512->37) + sigmoid + sequential normalize + dep-multiply.
// ---------------------------------------------------------------------------
__global__ __launch_bounds__(256)
void fc3_norm(const float* __restrict__ A, const float* __restrict__ W,
              const float* __restrict__ bias, float* __restrict__ out)
{
    __shared__ float sp[4][40];
    const int v = threadIdx.x >> 6, lane = threadIdx.x & 63;
    const int img = blockIdx.x * 4 + v;

    if (lane < 37) {
        const float4* a4 = (const float4*)(A + (size_t)img * 512);
        const float4* w4 = (const float4*)(W + (size_t)lane * 512);
        float s = bias[lane];
        #pragma unroll 4
        for (int k = 0; k < 128; ++k) {
            float4 a = a4[k], ww = w4[k];
            s = fmaf(a.x, ww.x, s); s = fmaf(a.y, ww.y, s);
            s = fmaf(a.z, ww.z, s); s = fmaf(a.w, ww.w, s);
        }
        sp[v][lane] = 1.f / (1.f + expf(-s));
    }
    __syncthreads();
    if (lane == 0) {
        float xv[37];
        #pragma unroll
        for (int i = 0; i < 37; ++i) xv[i] = sp[v][i];
        const int ss[11]  = {0, 3, 5, 7, 9, 13, 15, 18, 25, 28, 31};
        const int ee[11]  = {3, 5, 7, 9, 13, 15, 18, 25, 28, 31, 37};
        const int dep[11] = {-1, 1, 4, 4, 4, -1, 0, 13, 3, 7, 7};
        #pragma unroll
        for (int i = 0; i < 11; ++i) {
            for (int j = ss[i]; j < ee[i]; ++j) {
                float ssum = 0.f;
                for (int cix = ss[i]; cix < ee[i]; ++cix) ssum += xv[cix];
                xv[j] = xv[j] / (ssum + 1e-12f);
            }
        }
        #pragma unroll
        for (int i = 0; i < 11; ++i) {
            if (dep[i] >= 0) {
                const float m = xv[dep[i]];
                for (int cix = ss[i]; cix < ee[i]; ++cix) xv[cix] *= m;
            }
        }
        #pragma unroll
        for (int i = 0; i < 37; ++i) sp[v][i] = xv[i];
    }
    __syncthreads();
    if (lane < 37) out[(size_t)img * 37 + lane] = sp[v][lane];
}

// ---------------------------------------------------------------------------
extern "C" void kernel_launch(void* const* d_in, const int* in_sizes, int n_in,
                              void* d_out, int out_size, void* d_ws, size_t ws_size,
                              hipStream_t stream)
{
    const float* x   = (const float*)d_in[0];
    const float* c1w = (const float*)d_in[1];  const float* c1b = (const float*)d_in[2];
    const float* b1s = (const float*)d_in[3];  const float* b1b = (const float*)d_in[4];
    const float* b1m = (const float*)d_in[5];  const float* b1v = (const float*)d_in[6];
    const float* c2w = (const float*)d_in[7];  const float* c2b = (const float*)d_in[8];
    const float* b2s = (const float*)d_in[9];  const float* b2b = (const float*)d_in[10];
    const float* b2m = (const float*)d_in[11]; const float* b2v = (const float*)d_in[12];
    const float* c3w = (const float*)d_in[13]; const float* c3b = (const float*)d_in[14];
    const float* b3s = (const float*)d_in[15]; const float* b3b = (const float*)d_in[16];
    const float* b3m = (const float*)d_in[17]; const float* b3v = (const float*)d_in[18];
    const float* c4w = (const float*)d_in[19]; const float* c4b = (const float*)d_in[20];
    const float* b4s = (const float*)d_in[21]; const float* b4b = (const float*)d_in[22];
    const float* b4m = (const float*)d_in[23]; const float* b4v = (const float*)d_in[24];
    const float* f1w = (const float*)d_in[25]; const float* f1b = (const float*)d_in[26];
    const float* f2w = (const float*)d_in[27]; const float* f2b = (const float*)d_in[28];
    const float* f3w = (const float*)d_in[29]; const float* f3b = (const float*)d_in[30];

    // Workspace (bytes), peak ~81.7 MB:
    u16*   P2  = (u16*)d_ws;
    u16*   P3  = (u16*)((char*)d_ws + 44302336);
    u16*   P4  = (u16*)((char*)d_ws + 63176704);
    u16*   F1  = (u16*)((char*)d_ws + 69730304);
    float* F2  = (float*)((char*)d_ws + 71827456);
    u16*   W1b = (u16*)((char*)d_ws + 73924608);
    u16*   W2b = (u16*)((char*)d_ws + 80478208);
    u16*   W1t = (u16*)((char*)d_ws + 81526784);
    u16*   W2g = (u16*)((char*)d_ws + 81530880);
    u16*   W3g = (u16*)((char*)d_ws + 81556480);
    u16*   W4g = (u16*)((char*)d_ws + 81593344);

    prep_all<<<4130, 256, 0, stream>>>(c1w, c2w, c3w, c4w, f1w, f2w,
                                       W1t, W2g, W3g, W4g, W1b, W2b);

    conv12_fused<<<BATCH * 4, 512, 0, stream>>>(x, W1t, W2g, c1b, b1s, b1b, b1m, b1v,
                                                c2b, b2s, b2b, b2m, b2v, P2);
    conv3_mfma<<<BATCH * 2, 576, 0, stream>>>(P2, W3g, c3b, b3s, b3b, b3m, b3v, P3);
    conv4_mfma<<<BATCH * 4, 256, 0, stream>>>(P3, W4g, c4b, b4s, b4b, b4m, b4v, P4);

    fc_gemm_bf<false><<<dim3(16, 16), 256, 0, stream>>>(P4, W1b, f1b, F1, 1024, 1024, 3200);
    fc_gemm_bf<true ><<<dim3(8, 16),  256, 0, stream>>>(F1, W2b, f2b, F2, 1024, 512, 1024);
    fc3_norm<<<BATCH / 4, 256, 0, stream>>>(F2, f3w, f3b, (float*)d_out);
}